// Round 7
// baseline (255.665 us; speedup 1.0000x reference)
//
#include <hip/hip_runtime.h>

// Laplace transform forward: out[n,i,f] = e[i]*out[n-1,i,f] + decay[i]*inp[n,f]
// T=2048, F=256, N_S=108. float32 in / float32 out.
//
// R9 == R8 resubmitted (R8 bench was an infra failure: "container failed
// twice", no compile/test/profile evidence against the kernel).
//
// R8: contiguous-slice + load-free store burst (the untested cell of the
// pattern x loads 2x2). R5 (contiguous) was confounded by global loads in
// the loop (in-order vmcnt: each load waited on 27 prior store-acks) and
// 1-2 blocks/CU. R6 (load-free) reverted to strided per-wave i-rows.
// R8 phase C: block owns 4 consecutive n-slices; 27 register states/thread
// (st[k] <-> i=4k+w, f=lane*4); e/d in SGPRs (readfirstlane); 32 input rows
// in LDS; warm 0-28 exact steps from the 32-boundary ws state; then per n:
// 1 ds_read_b128 + 27 x {FMA + store}, k sweeping the 108KB slice in
// contiguous 4KB steps. Zero global loads in the burst; each block writes
// one sequential 432KB region. Grid 512 = 2 blocks/CU, fully co-resident.
// NT stores: twice-convicted regression (R3->R4 -10.7us, R6->R7 +11.8us);
// plain stores throughout.
// Kernel floor: 226.5MB / 6.3TB/s ~= 36us.

#define T_LEN 2048
#define F_DIM 256
#define NS    108      // NTAU + 2*K = 100 + 8
#define KPAD  4
#define CH    32            // A/B chunk length
#define NB    (T_LEN / CH)  // 64
#define CHC   4             // phase C slices per block
#define NBC   (T_LEN / CHC) // 512 blocks
#define NJ    27            // i-slots per thread

#define STATE_FLOATS ((size_t)NB * NS * 64 * 4)   // 1,769,472 floats
// const table lives at ws + STATE_FLOATS: [e:108][d:108][g:108]

typedef float f32x4 __attribute__((ext_vector_type(4)));

__device__ __forceinline__ void laplace_consts(int i, float& s, float& e, float& decay) {
    const float c   = powf(20.0f, 1.0f / 99.0f) - 1.0f;
    const float tau = powf(1.0f + c, (float)(i - KPAD));
    s     = 4.0f / tau;
    e     = expf(-s);
    decay = (1.0f - e) / s;
}

// ws slot for (chunk b, taustar i, f4-group lane): float4
__device__ __forceinline__ size_t ws_idx(int b, int i, int lane) {
    return (((size_t)b * NS + i) * 64 + lane) * 4;
}

__device__ __forceinline__ float sgpr_bcast(float x) {
    return __int_as_float(__builtin_amdgcn_readfirstlane(__float_as_int(x)));
}

// init: compute per-taustar constants once (1 block).
__global__ __launch_bounds__(128) void laplace_init(float* __restrict__ tab) {
    const int i = threadIdx.x;
    if (i < NS) {
        float s, e, d;
        laplace_consts(i, s, e, d);
        tab[i]          = e;
        tab[NS + i]     = d;
        tab[2 * NS + i] = expf(-s * (float)CH);   // g = e^CH
    }
}

// Phase A: local 32-step scan from zero state -> L_b
__global__ __launch_bounds__(256) void laplace_local(
    const float* __restrict__ inp,   // (T, F)
    float* __restrict__ ws,          // (NB, NS, 64) float4
    const float* __restrict__ tab)
{
    const int lane = threadIdx.x & 63;
    const int i    = blockIdx.y * 4 + (threadIdx.x >> 6);
    const int b    = blockIdx.x;

    const float e = tab[i];
    const float d = tab[NS + i];

    const float* ip = inp + lane * 4;
    float t0 = 0.f, t1 = 0.f, t2 = 0.f, t3 = 0.f;

    const int n0 = b * CH;
    #pragma unroll 8
    for (int n = n0; n < n0 + CH; ++n) {
        f32x4 x = *(const f32x4*)(ip + (size_t)n * F_DIM);
        t0 = fmaf(e, t0, d * x.x);
        t1 = fmaf(e, t1, d * x.y);
        t2 = fmaf(e, t2, d * x.z);
        t3 = fmaf(e, t3, d * x.w);
    }
    f32x4 r; r.x = t0; r.y = t1; r.z = t2; r.w = t3;
    *(f32x4*)(ws + ws_idx(b, i, lane)) = r;
}

// Phase B: in-place combine -> ws[b] = EXACT state entering chunk b
__global__ __launch_bounds__(256) void laplace_combine(
    float* __restrict__ ws,
    const float* __restrict__ tab)
{
    const int lane = threadIdx.x & 63;
    const int i    = blockIdx.x * 4 + (threadIdx.x >> 6);

    const float g = tab[2 * NS + i];

    float S0 = 0.f, S1 = 0.f, S2 = 0.f, S3 = 0.f;
    #pragma unroll 8
    for (int b = 0; b < NB; ++b) {
        f32x4* p = (f32x4*)(ws + ws_idx(b, i, lane));
        f32x4 L = *p;
        f32x4 S; S.x = S0; S.y = S1; S.z = S2; S.w = S3;
        *p = S;
        S0 = fmaf(g, S0, L.x);
        S1 = fmaf(g, S1, L.y);
        S2 = fmaf(g, S2, L.z);
        S3 = fmaf(g, S3, L.w);
    }
}

// Phase C (R8): contiguous-slice, load-free burst.
// Block b2 owns n in [4*b2, 4*b2+4), ALL 108 i. Thread (w,lane) carries
// st[k] = state for (i=4k+w, f=lane*4). Per n the block writes one
// contiguous 108KB slice in 4KB k-steps; per block one sequential 432KB
// region. No global loads after the prologue.
__global__ __launch_bounds__(256) void laplace_slice2(
    const float* __restrict__ inp,
    const float* __restrict__ ws,
    const float* __restrict__ tab,
    float* __restrict__ out)         // (T, NS, F)
{
    __shared__ float xs[CH][F_DIM];  // 32 KB: input rows [base, base+32)

    const int tid  = threadIdx.x;
    const int w    = tid >> 6;          // wave 0..3 (wave-uniform)
    const int lane = tid & 63;
    const int f0   = lane * 4;
    const int b2   = blockIdx.x;        // 0..511
    const int n0   = b2 * CHC;
    const int b32  = n0 >> 5;           // enclosing 32-chunk
    const int base = b32 * CH;
    const int warm = n0 - base;         // 0,4,...,28 (block-uniform)

    // stage the 32 enclosing input rows (wave w: rows w*8..w*8+7, 1KB each)
    const float* ip = inp + (size_t)base * F_DIM + f0;
    f32x4 v[8];
    #pragma unroll
    for (int r = 0; r < 8; ++r)
        v[r] = *(const f32x4*)(ip + (size_t)(w * 8 + r) * F_DIM);
    #pragma unroll
    for (int r = 0; r < 8; ++r)
        *(f32x4*)(&xs[w * 8 + r][f0]) = v[r];

    // wave-uniform constants -> SGPRs (keeps VGPRs for the 27 states)
    float eS[NJ], dS[NJ];
    #pragma unroll
    for (int k = 0; k < NJ; ++k) {
        eS[k] = sgpr_bcast(tab[4 * k + w]);
        dS[k] = sgpr_bcast(tab[NS + 4 * k + w]);
    }

    // exact entering states at the 32-boundary (coalesced 1KB/wave per k)
    f32x4 st[NJ];
    #pragma unroll
    for (int k = 0; k < NJ; ++k)
        st[k] = *(const f32x4*)(ws + ws_idx(b32, 4 * k + w, lane));

    __syncthreads();

    // warm: advance exactly base -> n0 (no stores; block-uniform trip count)
    for (int n = 0; n < warm; ++n) {
        f32x4 x = *(const f32x4*)(&xs[n][f0]);
        #pragma unroll
        for (int k = 0; k < NJ; ++k) {
            st[k].x = fmaf(eS[k], st[k].x, dS[k] * x.x);
            st[k].y = fmaf(eS[k], st[k].y, dS[k] * x.y);
            st[k].z = fmaf(eS[k], st[k].z, dS[k] * x.z);
            st[k].w = fmaf(eS[k], st[k].w, dS[k] * x.w);
        }
    }

    // burst: 4 slices; per n one ds_read_b128 + 27 x {FMA + store}.
    // Store addr: slice flat index = k*1024 + tid*4  <=>  (i=4k+w, f=lane*4).
    #pragma unroll
    for (int n = 0; n < CHC; ++n) {
        f32x4 x = *(const f32x4*)(&xs[warm + n][f0]);
        float* op = out + (size_t)(n0 + n) * (NS * F_DIM) + tid * 4;
        #pragma unroll
        for (int k = 0; k < NJ; ++k) {
            st[k].x = fmaf(eS[k], st[k].x, dS[k] * x.x);
            st[k].y = fmaf(eS[k], st[k].y, dS[k] * x.y);
            st[k].z = fmaf(eS[k], st[k].z, dS[k] * x.z);
            st[k].w = fmaf(eS[k], st[k].w, dS[k] * x.w);
            *(f32x4*)(op + (size_t)k * 1024) = st[k];
        }
    }
}

// Fallback (approximate warm-up), used only if ws is too small.
#define CHUNK_FB 64
#define WARM_FB  48
__global__ __launch_bounds__(256) void laplace_kernel_fb(
    const float* __restrict__ inp,
    float* __restrict__ out)
{
    const int tid  = threadIdx.x;
    const int lane = tid & 63;
    const int f0   = lane * 4;
    const int i    = blockIdx.y * 4 + (tid >> 6);
    const int n0   = blockIdx.x * CHUNK_FB;

    float s, e, decay;
    laplace_consts(i, s, e, decay);

    const float* ip = inp + f0;
    float t0 = 0.f, t1 = 0.f, t2 = 0.f, t3 = 0.f;

    int nstart = n0 - WARM_FB;
    if (nstart < 0) nstart = 0;
    #pragma unroll 4
    for (int n = nstart; n < n0; ++n) {
        f32x4 x = *(const f32x4*)(ip + (size_t)n * F_DIM);
        t0 = fmaf(e, t0, decay * x.x);
        t1 = fmaf(e, t1, decay * x.y);
        t2 = fmaf(e, t2, decay * x.z);
        t3 = fmaf(e, t3, decay * x.w);
    }
    float* op = out + (size_t)i * F_DIM + f0;
    #pragma unroll 4
    for (int n = n0; n < n0 + CHUNK_FB; ++n) {
        f32x4 x = *(const f32x4*)(ip + (size_t)n * F_DIM);
        t0 = fmaf(e, t0, decay * x.x);
        t1 = fmaf(e, t1, decay * x.y);
        t2 = fmaf(e, t2, decay * x.z);
        t3 = fmaf(e, t3, decay * x.w);
        f32x4 r; r.x = t0; r.y = t1; r.z = t2; r.w = t3;
        *(f32x4*)(op + (size_t)n * (NS * F_DIM)) = r;
    }
}

extern "C" void kernel_launch(void* const* d_in, const int* in_sizes, int n_in,
                              void* d_out, int out_size, void* d_ws, size_t ws_size,
                              hipStream_t stream) {
    const float* inp = (const float*)d_in[0];
    float* out = (float*)d_out;

    const size_t ws_need = (STATE_FLOATS + 3 * NS) * sizeof(float);  // ~7.08 MB

    if (d_ws != nullptr && ws_size >= ws_need) {
        float* ws  = (float*)d_ws;
        float* tab = ws + STATE_FLOATS;
        laplace_init   <<<dim3(1),          128, 0, stream>>>(tab);
        laplace_local  <<<dim3(NB, NS / 4), 256, 0, stream>>>(inp, ws, tab);
        laplace_combine<<<dim3(NS / 4),     256, 0, stream>>>(ws, tab);
        laplace_slice2 <<<dim3(NBC),        256, 0, stream>>>(inp, ws, tab, out);
    } else {
        laplace_kernel_fb<<<dim3(T_LEN / CHUNK_FB, NS / 4), 256, 0, stream>>>(inp, out);
    }
}